// Round 7
// baseline (315.812 us; speedup 1.0000x reference)
//
#include <hip/hip_runtime.h>
#include <math.h>

// Problem constants (fixed by reference)
#define NN   10000
#define EE   160000
#define GG   128
#define HIDK 25
#define KROWS 32     // 25 MLP rows + 1 b2 row (k=25) + 6 zero-pad rows
#define DOUT 32
#define EPSBN 1e-5f

// ---------------- workspace layout (float offsets) ----------------
// zeroed region (one hipMemsetAsync, ~97 KB):
#define OFF_CUR   0          // NN ints (scatter cursors)
#define OFF_GSUM  10016      // G*32
#define OFF_GCNT  14112      // G
#define OFF_DEGC  14240      // NN ints (degree counts)
#define ZERO_FLOATS 24256
// non-zeroed:
#define OFF_MOP   24256      // 64*12 moment partials
#define OFF_W1F   25024      // 75 (padded 80)
#define OFF_B1F   25104      // 25 (padded 32)
#define OFF_ROW   25136      // NN+1 ints (CSR row starts, padded 10016)
#define OFF_SRC   35152      // E ints (CSR src per slot)
#define OFF_EID   195152     // E ints (CSR edge id per slot)
#define OFF_WB0   355152     // 32*16*32 = 16384  ([k][i4][o][c] packed)
#define OFF_WB1   371536     // 32*32*32 = 32768
#define OFF_H     404304     // E*32 = 5,120,000 (h in CSR-slot order)
#define OFF_X1    5524304    // N*32
#define OFF_X2    5844304    // N*32
#define TOTAL_FLOATS 6164304 // ~24.7 MB of d_ws

__device__ inline float wave_red(float v) {
    for (int off = 32; off; off >>= 1) v += __shfl_down(v, off);
    return v;
}

// ---- stage 1: per-block moment partials (atomic-free)
__global__ void k_moments(const float* __restrict__ ea, float* __restrict__ mop) {
    __shared__ float ls[4][9];
    float s[9];
#pragma unroll
    for (int j = 0; j < 9; j++) s[j] = 0.f;
    int t = threadIdx.x;
    for (int e = blockIdx.x * 256 + t; e < EE; e += 64 * 256) {
        float a0 = ea[3 * e], a1 = ea[3 * e + 1], a2 = ea[3 * e + 2];
        s[0] += a0; s[1] += a1; s[2] += a2;
        s[3] += a0 * a0; s[4] += a0 * a1; s[5] += a0 * a2;
        s[6] += a1 * a1; s[7] += a1 * a2; s[8] += a2 * a2;
    }
    int w = t >> 6, lane = t & 63;
#pragma unroll
    for (int j = 0; j < 9; j++) {
        float r = wave_red(s[j]);
        if (lane == 0) ls[w][j] = r;
    }
    __syncthreads();
    if (t < 9) {
        float r = ls[0][t] + ls[1][t] + ls[2][t] + ls[3][t];
        mop[blockIdx.x * 12 + t] = r;
    }
}

// ---- in-degree (dst) counts
__global__ void k_deg(const int* __restrict__ ei, int* __restrict__ degc) {
    int e = blockIdx.x * blockDim.x + threadIdx.x;
    if (e < EE) atomicAdd(degc + ei[EE + e], 1);
}

// ---- single-block exclusive scan of degc -> row_start[NN+1]
__global__ void k_scan(const int* __restrict__ degc, int* __restrict__ row_start) {
    __shared__ int p[256];
    int t = threadIdx.x;
    const int CHUNK = 40;                 // 250*40 == 10000 exactly
    int base = t * CHUNK;
    int sum = 0;
    if (t < 250) {
        for (int i = 0; i < CHUNK; i++) sum += degc[base + i];
    }
    p[t] = sum;
    __syncthreads();
    for (int off = 1; off < 256; off <<= 1) {
        int v = (t >= off) ? p[t - off] : 0;
        __syncthreads();
        p[t] += v;
        __syncthreads();
    }
    int excl = p[t] - sum;
    if (t < 250) {
        int run = excl;
        for (int i = 0; i < CHUNK; i++) {
            row_start[base + i] = run;
            run += degc[base + i];
        }
    }
    if (t == 0) row_start[NN] = EE;
}

// ---- scatter edges into CSR slots
__global__ void k_scatter(const int* __restrict__ ei, const int* __restrict__ row_start,
                          int* __restrict__ cur, int* __restrict__ csr_src,
                          int* __restrict__ csr_eid) {
    int e = blockIdx.x * blockDim.x + threadIdx.x;
    if (e >= EE) return;
    int d = ei[EE + e];
    int pos = atomicAdd(cur + d, 1);
    int idx = row_start[d] + pos;
    csr_src[idx] = ei[e];
    csr_eid[idx] = e;
}

// ---- fold BN (analytic stats from partials) into w1', b1'
__global__ void k_fold(const float* __restrict__ mop, const float* __restrict__ w1,
                       const float* __restrict__ b1, const float* __restrict__ g,
                       const float* __restrict__ be, float* __restrict__ w1f,
                       float* __restrict__ b1f) {
    __shared__ float mo[9];
    int j = threadIdx.x;
    if (j < 9) {
        float s = 0.f;
        for (int b = 0; b < 64; b++) s += mop[b * 12 + j];
        mo[j] = s;
    }
    __syncthreads();
    if (j >= HIDK) return;
    const float inv = 1.0f / (float)EE;
    float m0 = mo[0] * inv, m1 = mo[1] * inv, m2 = mo[2] * inv;
    float c00 = mo[3] * inv - m0 * m0, c01 = mo[4] * inv - m0 * m1, c02 = mo[5] * inv - m0 * m2;
    float c11 = mo[6] * inv - m1 * m1, c12 = mo[7] * inv - m1 * m2, c22 = mo[8] * inv - m2 * m2;
    float w0 = w1[j], wa = w1[25 + j], wb = w1[50 + j];
    float mean = m0 * w0 + m1 * wa + m2 * wb + b1[j];
    float var = w0 * w0 * c00 + wa * wa * c11 + wb * wb * c22
              + 2.f * (w0 * wa * c01 + w0 * wb * c02 + wa * wb * c12);
    float sc = g[j] * rsqrtf(var + EPSBN);
    w1f[j] = w0 * sc; w1f[25 + j] = wa * sc; w1f[50 + j] = wb * sc;
    b1f[j] = (b1[j] - mean) * sc + be[j];
}

// ---- pack wbig2[k][i4][o][c] = w2[k][i4*4+c][o]; row 25 = b2; rows 26..31 = 0
template <int DIN>
__global__ void k_wprep(const float* __restrict__ w2, const float* __restrict__ b2,
                        float* __restrict__ wbig) {
    int idx = blockIdx.x * 256 + threadIdx.x;
    if (idx >= KROWS * DIN * DOUT) return;
    int k = idx / (DIN * DOUT);
    int rem = idx - k * (DIN * DOUT);
    int i4 = rem / (4 * DOUT);
    int rem2 = rem - i4 * (4 * DOUT);
    int o = rem2 >> 2, c = rem2 & 3;
    int i = i4 * 4 + c;
    float v = 0.f;
    if (k < HIDK) v = w2[(k * DIN + i) * DOUT + o];
    else if (k == HIDK) v = b2[i * DOUT + o];
    wbig[idx] = v;
}

// ---- h in CSR-slot order: hcsr[slot][k] = relu(ea[eid]@w1f+b1f)[k]; k=25 -> 1; pad -> 0
__global__ void k_h(const float* __restrict__ ea, const int* __restrict__ csr_eid,
                    const float* __restrict__ w1f, const float* __restrict__ b1f,
                    float* __restrict__ hcsr) {
    int t = threadIdx.x;
    int slot = blockIdx.x * 8 + (t >> 5);   // 20000 blocks exactly
    int k = t & 31;
    int e = csr_eid[slot];
    float v = 0.f;
    if (k < HIDK) {
        float a0 = ea[3 * e], a1 = ea[3 * e + 1], a2 = ea[3 * e + 2];
        v = a0 * w1f[k] + a1 * w1f[25 + k] + a2 * w1f[50 + k] + b1f[k];
        v = v > 0.f ? v : 0.f;
    } else if (k == HIDK) {
        v = 1.0f;
    }
    hcsr[(size_t)slot * 32 + k] = v;
}

// ---- FUSED layer kernel. One wave per dst node.
// Phase A: S[k][i] = sum_slot h[slot][k] * x[src[slot], i], S in registers
//   (lane layout: il = lane & (DIN-1), kh = lane/DIN owns k = kh*KPL..+KPL-1).
//   h read as broadcast float4 from hcsr (CSR order, no eid indirection),
//   edges unrolled x2 for MLP. No shuffles.
// Phase B: S -> LDS; out[o] = sum_{k,i} S[k,i]*wbig2[k][i4][o][.] + root + ELU.
template <int DIN, int KPL>
__global__ void k_fused(const int* __restrict__ row_start,
                        const int* __restrict__ csr_src,
                        const float* __restrict__ hcsr,
                        const float* __restrict__ wbig, const float* __restrict__ xin,
                        const float* __restrict__ wr, const float* __restrict__ bc,
                        float* __restrict__ xout) {
    __shared__ __align__(16) float Slds[4][KROWS][DIN];
    int t = threadIdx.x;
    int w = t >> 6;
    int lane = t & 63;
    int n = blockIdx.x * 4 + w;            // grid 2500 -> n in [0,10000)
    int start = row_start[n];
    int cnt = row_start[n + 1] - start;

    // ---- Phase A ----
    int il = lane & (DIN - 1);
    int kh = lane / DIN;                   // din32: 0..1 (KPL=16); din16: 0..3 (KPL=8)
    float s[KPL];
#pragma unroll
    for (int j = 0; j < KPL; j++) s[j] = 0.f;

    for (int p = 0; p < cnt; p += 2) {
        // hoist all loads for 2 edges, then FMA
        int qA = start + p;
        bool vB = (p + 1) < cnt;
        int qB = vB ? (qA + 1) : qA;
        int sA = csr_src[qA];
        int sB = csr_src[qB];
        const float4* hA = (const float4*)(hcsr + (size_t)qA * 32 + kh * KPL);
        const float4* hB = (const float4*)(hcsr + (size_t)qB * 32 + kh * KPL);
        float4 ha[KPL / 4], hb[KPL / 4];
#pragma unroll
        for (int j4 = 0; j4 < KPL / 4; j4++) { ha[j4] = hA[j4]; hb[j4] = hB[j4]; }
        float xA = xin[sA * DIN + il];
        float xB = xin[sB * DIN + il];
        if (!vB) xB = 0.f;
#pragma unroll
        for (int j4 = 0; j4 < KPL / 4; j4++) {
            s[j4 * 4 + 0] += ha[j4].x * xA; s[j4 * 4 + 1] += ha[j4].y * xA;
            s[j4 * 4 + 2] += ha[j4].z * xA; s[j4 * 4 + 3] += ha[j4].w * xA;
        }
#pragma unroll
        for (int j4 = 0; j4 < KPL / 4; j4++) {
            s[j4 * 4 + 0] += hb[j4].x * xB; s[j4 * 4 + 1] += hb[j4].y * xB;
            s[j4 * 4 + 2] += hb[j4].z * xB; s[j4 * 4 + 3] += hb[j4].w * xB;
        }
    }
#pragma unroll
    for (int j = 0; j < KPL; j++)
        Slds[w][kh * KPL + j][il] = s[j];
    __syncthreads();

    // ---- Phase B ----
    int o = lane & 31, half = lane >> 5;   // halves split KROWS as 16+16
    const float4* wb4 = (const float4*)wbig;
    float acc = 0.f;
    for (int kk = 0; kk < KROWS / 2; kk++) {
        int k = half * (KROWS / 2) + kk;
#pragma unroll
        for (int i4 = 0; i4 < DIN / 4; i4++) {
            float4 sv = *(const float4*)&Slds[w][k][i4 * 4];
            float4 wv = wb4[(k * (DIN / 4) + i4) * 32 + o];
            acc += sv.x * wv.x + sv.y * wv.y + sv.z * wv.z + sv.w * wv.w;
        }
    }
    acc += __shfl_xor(acc, 32);            // combine halves
    if (half == 0) {
        float d = (float)cnt; if (d < 1.f) d = 1.f;
        float r = acc / d + bc[o];
#pragma unroll
        for (int i = 0; i < DIN; i++) r += xin[n * DIN + i] * wr[i * DOUT + o];
        r = r > 0.f ? r : expm1f(r);
        xout[n * DOUT + o] = r;
    }
}

// ---- global mean pool accumulation
__global__ void k_pool(const float* __restrict__ x, const int* __restrict__ batch,
                       float* __restrict__ gsum, float* __restrict__ gcnt) {
    int idx = blockIdx.x * blockDim.x + threadIdx.x;
    if (idx >= NN * DOUT) return;
    int n = idx >> 5, o = idx & 31;
    int b = batch[n];
    atomicAdd(gsum + b * DOUT + o, x[idx]);
    if (o == 0) atomicAdd(gcnt + b, 1.0f);
}

// ---- final fc
__global__ void k_fc(const float* __restrict__ gsum, const float* __restrict__ gcnt,
                     const float* __restrict__ wfc, const float* __restrict__ bfc,
                     float* __restrict__ out) {
    int g = threadIdx.x;
    if (g >= GG) return;
    float c = gcnt[g]; c = c < 1.f ? 1.f : c;
    float acc = 0.f;
#pragma unroll
    for (int o = 0; o < DOUT; o++) acc += gsum[g * DOUT + o] * wfc[o];
    out[g] = acc / c + bfc[0];
}

extern "C" void kernel_launch(void* const* d_in, const int* in_sizes, int n_in,
                              void* d_out, int out_size, void* d_ws, size_t ws_size,
                              hipStream_t stream) {
    const float* x     = (const float*)d_in[0];
    const float* ea    = (const float*)d_in[1];
    const int*   ei    = (const int*)d_in[2];
    const int*   batch = (const int*)d_in[3];
    const float* w1_0 = (const float*)d_in[4];
    const float* b1_0 = (const float*)d_in[5];
    const float* g_0  = (const float*)d_in[6];
    const float* be_0 = (const float*)d_in[7];
    const float* w2_0 = (const float*)d_in[8];
    const float* b2_0 = (const float*)d_in[9];
    const float* wr_0 = (const float*)d_in[10];
    const float* bc_0 = (const float*)d_in[11];
    const float* w1_1 = (const float*)d_in[12];
    const float* b1_1 = (const float*)d_in[13];
    const float* g_1  = (const float*)d_in[14];
    const float* be_1 = (const float*)d_in[15];
    const float* w2_1 = (const float*)d_in[16];
    const float* b2_1 = (const float*)d_in[17];
    const float* wr_1 = (const float*)d_in[18];
    const float* bc_1 = (const float*)d_in[19];
    const float* wfc  = (const float*)d_in[20];
    const float* bfc  = (const float*)d_in[21];

    float* ws    = (float*)d_ws;
    int*   cur   = (int*)(ws + OFF_CUR);
    float* gsum  = ws + OFF_GSUM;
    float* gcnt  = ws + OFF_GCNT;
    int*   degc  = (int*)(ws + OFF_DEGC);
    float* mop   = ws + OFF_MOP;
    float* w1f   = ws + OFF_W1F;
    float* b1f   = ws + OFF_B1F;
    int*   row   = (int*)(ws + OFF_ROW);
    int*   csrc  = (int*)(ws + OFF_SRC);
    int*   ceid  = (int*)(ws + OFF_EID);
    float* wb0   = ws + OFF_WB0;
    float* wb1   = ws + OFF_WB1;
    float* hcsr  = ws + OFF_H;
    float* x1    = ws + OFF_X1;
    float* x2    = ws + OFF_X2;

    hipMemsetAsync(ws, 0, (size_t)ZERO_FLOATS * sizeof(float), stream);

    k_moments<<<64, 256, 0, stream>>>(ea, mop);
    k_deg<<<(EE + 255) / 256, 256, 0, stream>>>(ei, degc);
    k_scan<<<1, 256, 0, stream>>>(degc, row);
    k_scatter<<<(EE + 255) / 256, 256, 0, stream>>>(ei, row, cur, csrc, ceid);
    k_wprep<16><<<(KROWS * 16 * DOUT + 255) / 256, 256, 0, stream>>>(w2_0, b2_0, wb0);
    k_wprep<32><<<(KROWS * 32 * DOUT + 255) / 256, 256, 0, stream>>>(w2_1, b2_1, wb1);

    // ---- layer 0 (din=16)
    k_fold<<<1, 64, 0, stream>>>(mop, w1_0, b1_0, g_0, be_0, w1f, b1f);
    k_h<<<EE / 8, 256, 0, stream>>>(ea, ceid, w1f, b1f, hcsr);
    k_fused<16, 8><<<NN / 4, 256, 0, stream>>>(row, csrc, hcsr, wb0, x, wr_0, bc_0, x1);

    // ---- layer 1 (din=32)
    k_fold<<<1, 64, 0, stream>>>(mop, w1_1, b1_1, g_1, be_1, w1f, b1f);
    k_h<<<EE / 8, 256, 0, stream>>>(ea, ceid, w1f, b1f, hcsr);
    k_fused<32, 16><<<NN / 4, 256, 0, stream>>>(row, csrc, hcsr, wb1, x1, wr_1, bc_1, x2);

    // ---- pool + fc
    k_pool<<<(NN * DOUT + 255) / 256, 256, 0, stream>>>(x2, batch, gsum, gcnt);
    k_fc<<<1, 128, 0, stream>>>(gsum, gcnt, wfc, bfc, (float*)d_out);
}

// Round 8
// 277.270 us; speedup vs baseline: 1.1390x; 1.1390x over previous
//
#include <hip/hip_runtime.h>
#include <math.h>

// Problem constants (fixed by reference)
#define NN   10000
#define EE   160000
#define GG   128
#define HIDK 25
#define KROWS 32     // 25 MLP rows + 1 b2 row (k=25) + 6 zero-pad rows
#define DOUT 32
#define EPSBN 1e-5f

// ---------------- workspace layout (float offsets) ----------------
// zeroed region (one hipMemsetAsync):
#define OFF_CUR   0          // NN ints (scatter cursors), pad 10016
#define OFF_GSUM  10016      // G*32 = 4096
#define OFF_DEGC  14112      // NN ints, pad 10016
#define ZERO_FLOATS 24128
// non-zeroed:
#define OFF_MOP   24128      // 64*12
#define OFF_W1F0  24896      // 80
#define OFF_B1F0  24976      // 32
#define OFF_W1F1  25008      // 80
#define OFF_B1F1  25088      // 32
#define OFF_ROW   25120      // NN+1 ints, pad 10016
#define OFF_SRC   35136      // E ints
#define OFF_EID   195136     // E ints
#define OFF_WB0   355136     // 32*16*32 = 16384
#define OFF_WB1   371520     // 32*32*32 = 32768
#define OFF_H     404288     // E*32 = 5,120,000 (h in CSR-slot order, one layer at a time)
#define OFF_X1    5524288    // N*32
#define TOTAL_FLOATS 5844288 // ~23.4 MB of d_ws

__device__ inline float wave_red(float v) {
    for (int off = 32; off; off >>= 1) v += __shfl_down(v, off);
    return v;
}

// ---- moments partials (64 blocks, atomic-free) + in-degree atomics, one pass
__global__ void k_momdeg(const float* __restrict__ ea, const int* __restrict__ ei,
                         float* __restrict__ mop, int* __restrict__ degc) {
    __shared__ float ls[4][9];
    float s[9];
#pragma unroll
    for (int j = 0; j < 9; j++) s[j] = 0.f;
    int t = threadIdx.x;
    for (int e = blockIdx.x * 256 + t; e < EE; e += 64 * 256) {
        float a0 = ea[3 * e], a1 = ea[3 * e + 1], a2 = ea[3 * e + 2];
        s[0] += a0; s[1] += a1; s[2] += a2;
        s[3] += a0 * a0; s[4] += a0 * a1; s[5] += a0 * a2;
        s[6] += a1 * a1; s[7] += a1 * a2; s[8] += a2 * a2;
        atomicAdd(degc + ei[EE + e], 1);
    }
    int w = t >> 6, lane = t & 63;
#pragma unroll
    for (int j = 0; j < 9; j++) {
        float r = wave_red(s[j]);
        if (lane == 0) ls[w][j] = r;
    }
    __syncthreads();
    if (t < 9) mop[blockIdx.x * 12 + t] = ls[0][t] + ls[1][t] + ls[2][t] + ls[3][t];
}

// ---- single-block exclusive scan of degc -> row_start[NN+1]
__global__ void k_scan(const int* __restrict__ degc, int* __restrict__ row_start) {
    __shared__ int p[256];
    int t = threadIdx.x;
    const int CHUNK = 40;                 // 250*40 == 10000 exactly
    int base = t * CHUNK;
    int sum = 0;
    if (t < 250) {
        for (int i = 0; i < CHUNK; i++) sum += degc[base + i];
    }
    p[t] = sum;
    __syncthreads();
    for (int off = 1; off < 256; off <<= 1) {
        int v = (t >= off) ? p[t - off] : 0;
        __syncthreads();
        p[t] += v;
        __syncthreads();
    }
    int excl = p[t] - sum;
    if (t < 250) {
        int run = excl;
        for (int i = 0; i < CHUNK; i++) {
            row_start[base + i] = run;
            run += degc[base + i];
        }
    }
    if (t == 0) row_start[NN] = EE;
}

// ---- scatter edges into CSR slots
__global__ void k_scatter(const int* __restrict__ ei, const int* __restrict__ row_start,
                          int* __restrict__ cur, int* __restrict__ csr_src,
                          int* __restrict__ csr_eid) {
    int e = blockIdx.x * blockDim.x + threadIdx.x;
    if (e >= EE) return;
    int d = ei[EE + e];
    int pos = atomicAdd(cur + d, 1);
    int idx = row_start[d] + pos;
    csr_src[idx] = ei[e];
    csr_eid[idx] = e;
}

// ---- fold BN (analytic stats) into w1', b1' for BOTH layers (one launch)
__global__ void k_fold2(const float* __restrict__ mop,
                        const float* __restrict__ w1_0, const float* __restrict__ b1_0,
                        const float* __restrict__ g_0, const float* __restrict__ be_0,
                        const float* __restrict__ w1_1, const float* __restrict__ b1_1,
                        const float* __restrict__ g_1, const float* __restrict__ be_1,
                        float* __restrict__ w1f0, float* __restrict__ b1f0,
                        float* __restrict__ w1f1, float* __restrict__ b1f1) {
    __shared__ float mo[9];
    int t = threadIdx.x;
    if (t < 9) {
        float s = 0.f;
        for (int b = 0; b < 64; b++) s += mop[b * 12 + t];
        mo[t] = s;
    }
    __syncthreads();
    int grp = t >> 5, j = t & 31;
    if (j >= HIDK) return;
    const float* w1 = grp ? w1_1 : w1_0;
    const float* b1 = grp ? b1_1 : b1_0;
    const float* g  = grp ? g_1  : g_0;
    const float* be = grp ? be_1 : be_0;
    float* w1f = grp ? w1f1 : w1f0;
    float* b1f = grp ? b1f1 : b1f0;
    const float inv = 1.0f / (float)EE;
    float m0 = mo[0] * inv, m1 = mo[1] * inv, m2 = mo[2] * inv;
    float c00 = mo[3] * inv - m0 * m0, c01 = mo[4] * inv - m0 * m1, c02 = mo[5] * inv - m0 * m2;
    float c11 = mo[6] * inv - m1 * m1, c12 = mo[7] * inv - m1 * m2, c22 = mo[8] * inv - m2 * m2;
    float w0 = w1[j], wa = w1[25 + j], wb = w1[50 + j];
    float mean = m0 * w0 + m1 * wa + m2 * wb + b1[j];
    float var = w0 * w0 * c00 + wa * wa * c11 + wb * wb * c22
              + 2.f * (w0 * wa * c01 + w0 * wb * c02 + wa * wb * c12);
    float sc = g[j] * rsqrtf(var + EPSBN);
    w1f[j] = w0 * sc; w1f[25 + j] = wa * sc; w1f[50 + j] = wb * sc;
    b1f[j] = (b1[j] - mean) * sc + be[j];
}

// ---- pack wbig[k][i4][o][c] = w2[k][i4*4+c][o]; row 25 = b2; rows >= 26 = 0
template <int DIN>
__device__ inline void wpack(int idx, const float* __restrict__ w2,
                             const float* __restrict__ b2, float* __restrict__ wbig) {
    int k = idx / (DIN * DOUT);
    int rem = idx - k * (DIN * DOUT);
    int i4 = rem / (4 * DOUT);
    int rem2 = rem - i4 * (4 * DOUT);
    int o = rem2 >> 2, c = rem2 & 3;
    int i = i4 * 4 + c;
    float v = 0.f;
    if (k < HIDK) v = w2[(k * DIN + i) * DOUT + o];
    else if (k == HIDK) v = b2[i * DOUT + o];
    wbig[idx] = v;
}

__global__ void k_wprep2(const float* __restrict__ w2_0, const float* __restrict__ b2_0,
                         const float* __restrict__ w2_1, const float* __restrict__ b2_1,
                         float* __restrict__ wb0, float* __restrict__ wb1) {
    int idx = blockIdx.x * 256 + threadIdx.x;
    if (idx < KROWS * 16 * DOUT) wpack<16>(idx, w2_0, b2_0, wb0);
    else if (idx < KROWS * 16 * DOUT + KROWS * 32 * DOUT)
        wpack<32>(idx - KROWS * 16 * DOUT, w2_1, b2_1, wb1);
}

// ---- h in CSR-slot order: hcsr[slot][k] = relu(ea[eid]@w1f+b1f)[k]; k=25 -> 1; pad -> 0
__global__ void k_h(const float* __restrict__ ea, const int* __restrict__ csr_eid,
                    const float* __restrict__ w1f, const float* __restrict__ b1f,
                    float* __restrict__ hcsr) {
    int t = threadIdx.x;
    int slot = blockIdx.x * 8 + (t >> 5);   // 20000 blocks exactly
    int k = t & 31;
    int e = csr_eid[slot];
    float v = 0.f;
    if (k < HIDK) {
        float a0 = ea[3 * e], a1 = ea[3 * e + 1], a2 = ea[3 * e + 2];
        v = a0 * w1f[k] + a1 * w1f[25 + k] + a2 * w1f[50 + k] + b1f[k];
        v = v > 0.f ? v : 0.f;
    } else if (k == HIDK) {
        v = 1.0f;
    }
    hcsr[(size_t)slot * 32 + k] = v;
}

// ---- FUSED layer kernel. TWO waves per node (edge-parity split) to halve the
// serial gather chain and per-wave Phase-B work. Block = 4 waves = 2 nodes.
// Phase A: wave (node ln, parity q) accumulates partial S[k][i] in registers.
// Phase B: same wave pair covers the 32 k-rows (16 each, 8 per half-wave),
//   summing the two partial S from LDS. Cross-wave output combine via Olds.
// FINAL=true: epilogue atomicAdds into gsum (global mean pool), no xout store.
template <int DIN, int KPL, bool FINAL>
__global__ void k_fused(const int* __restrict__ row_start,
                        const int* __restrict__ csr_src,
                        const float* __restrict__ hcsr,
                        const float* __restrict__ wbig, const float* __restrict__ xin,
                        const float* __restrict__ wr, const float* __restrict__ bc,
                        const int* __restrict__ batch,
                        float* __restrict__ xout, float* __restrict__ gsum) {
    __shared__ __align__(16) float Slds[4][KROWS][DIN];
    __shared__ float Olds[4][DOUT];
    int t = threadIdx.x;
    int w = t >> 6, lane = t & 63;
    int ln = w >> 1, q = w & 1;
    int n = blockIdx.x * 2 + ln;           // grid 5000 -> n in [0,10000)
    int start = row_start[n], end = row_start[n + 1];

    // ---- Phase A (partial S over this wave's parity class of edges) ----
    int il = lane & (DIN - 1);
    int kh = lane / DIN;                   // 64/DIN k-groups
    float s[KPL];
#pragma unroll
    for (int j = 0; j < KPL; j++) s[j] = 0.f;

    for (int p = start + q; p < end; p += 4) {
        int qA = p;
        int qB = p + 2;
        bool vB = qB < end;
        int qBs = vB ? qB : qA;
        int sA = csr_src[qA];
        int sB = csr_src[qBs];
        const float4* hA4 = (const float4*)(hcsr + (size_t)qA * 32 + kh * KPL);
        const float4* hB4 = (const float4*)(hcsr + (size_t)qBs * 32 + kh * KPL);
        float4 ha[KPL / 4], hb[KPL / 4];
#pragma unroll
        for (int j4 = 0; j4 < KPL / 4; j4++) { ha[j4] = hA4[j4]; hb[j4] = hB4[j4]; }
        float xA = xin[sA * DIN + il];
        float xB = xin[sB * DIN + il];
        if (!vB) xB = 0.f;
#pragma unroll
        for (int j4 = 0; j4 < KPL / 4; j4++) {
            s[j4 * 4 + 0] += ha[j4].x * xA; s[j4 * 4 + 1] += ha[j4].y * xA;
            s[j4 * 4 + 2] += ha[j4].z * xA; s[j4 * 4 + 3] += ha[j4].w * xA;
        }
#pragma unroll
        for (int j4 = 0; j4 < KPL / 4; j4++) {
            s[j4 * 4 + 0] += hb[j4].x * xB; s[j4 * 4 + 1] += hb[j4].y * xB;
            s[j4 * 4 + 2] += hb[j4].z * xB; s[j4 * 4 + 3] += hb[j4].w * xB;
        }
    }
#pragma unroll
    for (int j = 0; j < KPL; j++)
        Slds[w][kh * KPL + j][il] = s[j];
    __syncthreads();

    // ---- Phase B ----
    int o = lane & 31, half = lane >> 5;
    const float4* wb4 = (const float4*)wbig;
    float acc = 0.f;
    int kbase = q * (KROWS / 2) + half * (KROWS / 4);
    for (int kk = 0; kk < KROWS / 4; kk++) {
        int k = kbase + kk;
#pragma unroll
        for (int i4 = 0; i4 < DIN / 4; i4++) {
            float4 s0 = *(const float4*)&Slds[2 * ln + 0][k][i4 * 4];
            float4 s1 = *(const float4*)&Slds[2 * ln + 1][k][i4 * 4];
            float4 wv = wb4[(k * (DIN / 4) + i4) * 32 + o];
            acc += (s0.x + s1.x) * wv.x + (s0.y + s1.y) * wv.y
                 + (s0.z + s1.z) * wv.z + (s0.w + s1.w) * wv.w;
        }
    }
    acc += __shfl_xor(acc, 32);            // combine halves (16 rows per wave)
    if (half == 0) Olds[w][o] = acc;
    __syncthreads();

    // ---- finalize (wave 0: 2 nodes x 32 lanes) ----
    if (t < 64) {
        int ln2 = t >> 5, o2 = t & 31;
        int n2 = blockIdx.x * 2 + ln2;
        int cnt2 = row_start[n2 + 1] - row_start[n2];
        float d = (float)cnt2; if (d < 1.f) d = 1.f;
        float r = (Olds[2 * ln2][o2] + Olds[2 * ln2 + 1][o2]) / d + bc[o2];
#pragma unroll
        for (int i = 0; i < DIN; i++) r += xin[n2 * DIN + i] * wr[i * DOUT + o2];
        r = r > 0.f ? r : expm1f(r);
        if (FINAL) atomicAdd(gsum + batch[n2] * DOUT + o2, r);
        else xout[n2 * DOUT + o2] = r;
    }
}

// ---- final fc; per-graph node counts via binary search on SORTED batch
__global__ void k_fc(const float* __restrict__ gsum, const int* __restrict__ batch,
                     const float* __restrict__ wfc, const float* __restrict__ bfc,
                     float* __restrict__ out) {
    int g = threadIdx.x;
    if (g >= GG) return;
    int lo = 0, hi = NN;
    while (lo < hi) { int mid = (lo + hi) >> 1; if (batch[mid] < g) lo = mid + 1; else hi = mid; }
    int lb = lo;
    lo = 0; hi = NN;
    while (lo < hi) { int mid = (lo + hi) >> 1; if (batch[mid] < g + 1) lo = mid + 1; else hi = mid; }
    float c = (float)(lo - lb); if (c < 1.f) c = 1.f;
    float acc = 0.f;
#pragma unroll
    for (int o = 0; o < DOUT; o++) acc += gsum[g * DOUT + o] * wfc[o];
    out[g] = acc / c + bfc[0];
}

extern "C" void kernel_launch(void* const* d_in, const int* in_sizes, int n_in,
                              void* d_out, int out_size, void* d_ws, size_t ws_size,
                              hipStream_t stream) {
    const float* x     = (const float*)d_in[0];
    const float* ea    = (const float*)d_in[1];
    const int*   ei    = (const int*)d_in[2];
    const int*   batch = (const int*)d_in[3];
    const float* w1_0 = (const float*)d_in[4];
    const float* b1_0 = (const float*)d_in[5];
    const float* g_0  = (const float*)d_in[6];
    const float* be_0 = (const float*)d_in[7];
    const float* w2_0 = (const float*)d_in[8];
    const float* b2_0 = (const float*)d_in[9];
    const float* wr_0 = (const float*)d_in[10];
    const float* bc_0 = (const float*)d_in[11];
    const float* w1_1 = (const float*)d_in[12];
    const float* b1_1 = (const float*)d_in[13];
    const float* g_1  = (const float*)d_in[14];
    const float* be_1 = (const float*)d_in[15];
    const float* w2_1 = (const float*)d_in[16];
    const float* b2_1 = (const float*)d_in[17];
    const float* wr_1 = (const float*)d_in[18];
    const float* bc_1 = (const float*)d_in[19];
    const float* wfc  = (const float*)d_in[20];
    const float* bfc  = (const float*)d_in[21];

    float* ws    = (float*)d_ws;
    int*   cur   = (int*)(ws + OFF_CUR);
    float* gsum  = ws + OFF_GSUM;
    int*   degc  = (int*)(ws + OFF_DEGC);
    float* mop   = ws + OFF_MOP;
    float* w1f0  = ws + OFF_W1F0;
    float* b1f0  = ws + OFF_B1F0;
    float* w1f1  = ws + OFF_W1F1;
    float* b1f1  = ws + OFF_B1F1;
    int*   row   = (int*)(ws + OFF_ROW);
    int*   csrc  = (int*)(ws + OFF_SRC);
    int*   ceid  = (int*)(ws + OFF_EID);
    float* wb0   = ws + OFF_WB0;
    float* wb1   = ws + OFF_WB1;
    float* hcsr  = ws + OFF_H;
    float* x1    = ws + OFF_X1;

    hipMemsetAsync(ws, 0, (size_t)ZERO_FLOATS * sizeof(float), stream);

    k_momdeg<<<64, 256, 0, stream>>>(ea, ei, mop, degc);
    k_scan<<<1, 256, 0, stream>>>(degc, row);
    k_scatter<<<(EE + 255) / 256, 256, 0, stream>>>(ei, row, cur, csrc, ceid);
    k_fold2<<<1, 64, 0, stream>>>(mop, w1_0, b1_0, g_0, be_0, w1_1, b1_1, g_1, be_1,
                                  w1f0, b1f0, w1f1, b1f1);
    k_wprep2<<<(KROWS * 48 * DOUT + 255) / 256, 256, 0, stream>>>(w2_0, b2_0, w2_1, b2_1, wb0, wb1);

    // ---- layer 0 (din=16)
    k_h<<<EE / 8, 256, 0, stream>>>(ea, ceid, w1f0, b1f0, hcsr);
    k_fused<16, 8, false><<<NN / 2, 256, 0, stream>>>(row, csrc, hcsr, wb0, x, wr_0, bc_0,
                                                      batch, x1, gsum);

    // ---- layer 1 (din=32), fused global-mean-pool epilogue
    k_h<<<EE / 8, 256, 0, stream>>>(ea, ceid, w1f1, b1f1, hcsr);
    k_fused<32, 16, true><<<NN / 2, 256, 0, stream>>>(row, csrc, hcsr, wb1, x1, wr_1, bc_1,
                                                      batch, nullptr, gsum);

    // ---- fc (counts via binary search on sorted batch)
    k_fc<<<1, 128, 0, stream>>>(gsum, batch, wfc, bfc, (float*)d_out);
}